// Round 1
// 1656.130 us; speedup vs baseline: 2.2209x; 2.2209x over previous
//
#include <hip/hip_runtime.h>
#include <cstdint>
#include <cstddef>

#define H 2048
#define F 5504
#define E 8
#define T 2048
#define ROWCAP 5120  // 4096 rows + 8*128 padding worst case

typedef __bf16 bf16x8 __attribute__((ext_vector_type(8)));
typedef float f32x4 __attribute__((ext_vector_type(4)));

#define AS1(p) ((const __attribute__((address_space(1))) void*)(p))
#define AS3(p) ((__attribute__((address_space(3))) void*)(p))

// ---------------- router: fp32 logits, top-2, softmax, slot assignment ----------------
__global__ void router_kernel(const float* __restrict__ x,
                              const float* __restrict__ rw,
                              int* __restrict__ cnt,
                              int* __restrict__ list_t,
                              float* __restrict__ list_w) {
    const int wv = threadIdx.x >> 6;
    const int lane = threadIdx.x & 63;
    const int t = blockIdx.x * 4 + wv;
    const float4* xp = (const float4*)(x + (size_t)t * H) + lane * 8;
    float4 xv[8];
#pragma unroll
    for (int i = 0; i < 8; ++i) xv[i] = xp[i];
    float lg[E];
#pragma unroll
    for (int e = 0; e < E; ++e) {
        const float4* wp = (const float4*)(rw + (size_t)e * H) + lane * 8;
        float acc = 0.f;
#pragma unroll
        for (int i = 0; i < 8; ++i) {
            float4 w4 = wp[i];
            acc += xv[i].x * w4.x + xv[i].y * w4.y + xv[i].z * w4.z + xv[i].w * w4.w;
        }
#pragma unroll
        for (int o = 32; o > 0; o >>= 1) acc += __shfl_xor(acc, o, 64);
        lg[e] = acc;
    }
    if (lane == 0) {
        float v0 = -3e38f, v1 = -3e38f;
        int i0 = 0, i1 = 0;
#pragma unroll
        for (int e = 0; e < E; ++e) {
            float v = lg[e];
            if (v > v0) { v1 = v0; i1 = i0; v0 = v; i0 = e; }
            else if (v > v1) { v1 = v; i1 = e; }
        }
        // softmax over the two selected logits (v0 >= v1)
        float p0 = 1.f / (1.f + __expf(v1 - v0));
        float p1 = 1.f - p0;
        int s0 = atomicAdd(&cnt[i0], 1);
        list_t[i0 * T + s0] = t;
        list_w[i0 * T + s0] = p0;
        int s1 = atomicAdd(&cnt[i1], 1);
        list_t[i1 * T + s1] = t;
        list_w[i1 * T + s1] = p1;
    }
}

// ---------------- prefix: 128-aligned per-expert offsets ----------------
__global__ void offsets_kernel(const int* __restrict__ cnt, int* __restrict__ off) {
    if (threadIdx.x == 0) {
        int acc = 0;
        for (int e = 0; e < E; ++e) {
            off[e] = acc;
            acc += (cnt[e] + 127) & ~127;
        }
    }
}

// ---------------- gather: pack x rows (fp32 -> bf16) per expert ----------------
__global__ void gather_kernel(const float* __restrict__ x,
                              const int* __restrict__ cnt,
                              const int* __restrict__ off,
                              const int* __restrict__ list_t,
                              const float* __restrict__ list_w,
                              __bf16* __restrict__ Abuf,
                              int* __restrict__ row_t,
                              float* __restrict__ row_w) {
    const int e = blockIdx.y, slot = blockIdx.x;
    if (slot >= cnt[e]) return;
    const int row = off[e] + slot;
    if (threadIdx.x == 0) {
        row_t[row] = list_t[e * T + slot];
        row_w[row] = list_w[e * T + slot];
    }
    const int t = list_t[e * T + slot];
    const float4* src = (const float4*)(x + (size_t)t * H);
    float4 a = src[threadIdx.x * 2], b = src[threadIdx.x * 2 + 1];
    bf16x8 o;
    o[0] = (__bf16)a.x; o[1] = (__bf16)a.y; o[2] = (__bf16)a.z; o[3] = (__bf16)a.w;
    o[4] = (__bf16)b.x; o[5] = (__bf16)b.y; o[6] = (__bf16)b.z; o[7] = (__bf16)b.w;
    *(bf16x8*)(Abuf + (size_t)row * H + threadIdx.x * 8) = o;
}

// ---------------- fused gate+up GEMM + SwiGLU epilogue ----------------
// C[m,n] = A[m,:] . W[n,:]  (NT), 128x128 tile, 4 waves, 16x16x32 bf16 MFMA
// __launch_bounds__(256, 2): 256-VGPR budget fits the ~220-reg working set
// (32 f32x4 accumulators + fragments) WITHOUT scratch spill; default (no
// bounds) capped at 128 regs -> spilled ~240B/thread/K-iter = 5.4 GB of
// scratch writes per dispatch (measured).
__global__ void __launch_bounds__(256, 2)
gateup_kernel(const __bf16* __restrict__ Abuf,
              const float* __restrict__ gw,
              const float* __restrict__ uw,
              const int* __restrict__ cnt,
              const int* __restrict__ off,
              const float* __restrict__ row_w,
              __bf16* __restrict__ act) {
    const int e = blockIdx.z;
    const int count = cnt[e];
    const int mt = blockIdx.y;
    if (mt * 128 >= count) return;
    const int n0 = blockIdx.x * 128;
    const int rowbase = off[e] + mt * 128;

    __shared__ __bf16 As[128 * 32];
    __shared__ __bf16 Gs[128 * 32];
    __shared__ __bf16 Us[128 * 32];

    const int tid = threadIdx.x;
    const int wv = tid >> 6, lane = tid & 63;
    const int wr = wv >> 1, wc = wv & 1;
    const int quad = lane >> 4, l16 = lane & 15;

    f32x4 accG[4][4] = {};
    f32x4 accU[4][4] = {};

    const __bf16* abase = Abuf + (size_t)rowbase * H;
    const float* gbase = gw + (size_t)e * F * H + (size_t)n0 * H;
    const float* ubase = uw + (size_t)e * F * H + (size_t)n0 * H;

    const int arow = lane >> 2;         // row within 16-row segment
    const int acol = (lane & 3) * 8;    // k-element offset (16B chunks)
    const int wrow = tid >> 1;          // 0..127
    const int kh = (tid & 1) * 16;      // 0 or 16

    for (int k0 = 0; k0 < H; k0 += 32) {
        // A tile via async global->LDS (16B/lane, lane-ordered contiguous)
#pragma unroll
        for (int i = 0; i < 2; ++i) {
            const int seg = wv * 2 + i;
            const __bf16* gp = abase + (size_t)(seg * 16 + arow) * H + k0 + acol;
            __builtin_amdgcn_global_load_lds(AS1(gp), AS3(As + seg * 512), 16, 0, 0);
        }
        // W tiles: fp32 load -> bf16 convert -> LDS
        {
            const float4* gp = (const float4*)(gbase + (size_t)wrow * H + k0 + kh);
            float4 f0 = gp[0], f1 = gp[1], f2 = gp[2], f3 = gp[3];
            bf16x8 h0, h1;
            h0[0] = (__bf16)f0.x; h0[1] = (__bf16)f0.y; h0[2] = (__bf16)f0.z; h0[3] = (__bf16)f0.w;
            h0[4] = (__bf16)f1.x; h0[5] = (__bf16)f1.y; h0[6] = (__bf16)f1.z; h0[7] = (__bf16)f1.w;
            h1[0] = (__bf16)f2.x; h1[1] = (__bf16)f2.y; h1[2] = (__bf16)f2.z; h1[3] = (__bf16)f2.w;
            h1[4] = (__bf16)f3.x; h1[5] = (__bf16)f3.y; h1[6] = (__bf16)f3.z; h1[7] = (__bf16)f3.w;
            *(bf16x8*)(Gs + wrow * 32 + kh) = h0;
            *(bf16x8*)(Gs + wrow * 32 + kh + 8) = h1;
            const float4* up = (const float4*)(ubase + (size_t)wrow * H + k0 + kh);
            f0 = up[0]; f1 = up[1]; f2 = up[2]; f3 = up[3];
            h0[0] = (__bf16)f0.x; h0[1] = (__bf16)f0.y; h0[2] = (__bf16)f0.z; h0[3] = (__bf16)f0.w;
            h0[4] = (__bf16)f1.x; h0[5] = (__bf16)f1.y; h0[6] = (__bf16)f1.z; h0[7] = (__bf16)f1.w;
            h1[0] = (__bf16)f2.x; h1[1] = (__bf16)f2.y; h1[2] = (__bf16)f2.z; h1[3] = (__bf16)f2.w;
            h1[4] = (__bf16)f3.x; h1[5] = (__bf16)f3.y; h1[6] = (__bf16)f3.z; h1[7] = (__bf16)f3.w;
            *(bf16x8*)(Us + wrow * 32 + kh) = h0;
            *(bf16x8*)(Us + wrow * 32 + kh + 8) = h1;
        }
        __syncthreads();

        bf16x8 af[4], gf[4], uf[4];
#pragma unroll
        for (int i = 0; i < 4; ++i)
            af[i] = *(const bf16x8*)(As + (wr * 64 + i * 16 + l16) * 32 + quad * 8);
#pragma unroll
        for (int j = 0; j < 4; ++j) {
            gf[j] = *(const bf16x8*)(Gs + (wc * 64 + j * 16 + l16) * 32 + quad * 8);
            uf[j] = *(const bf16x8*)(Us + (wc * 64 + j * 16 + l16) * 32 + quad * 8);
        }
#pragma unroll
        for (int i = 0; i < 4; ++i)
#pragma unroll
            for (int j = 0; j < 4; ++j) {
                accG[i][j] = __builtin_amdgcn_mfma_f32_16x16x32_bf16(af[i], gf[j], accG[i][j], 0, 0, 0);
                accU[i][j] = __builtin_amdgcn_mfma_f32_16x16x32_bf16(af[i], uf[j], accU[i][j], 0, 0, 0);
            }
        __syncthreads();
    }

    // epilogue: act = silu(g) * u * combine_w  (combine weight folded here)
#pragma unroll
    for (int i = 0; i < 4; ++i) {
        const int ml = wr * 64 + i * 16 + quad * 4;
#pragma unroll
        for (int r = 0; r < 4; ++r) {
            const float w = row_w[rowbase + ml + r];
            __bf16* arow_p = act + (size_t)(rowbase + ml + r) * F + n0;
#pragma unroll
            for (int j = 0; j < 4; ++j) {
                const int nl = wc * 64 + j * 16 + l16;
                float g = accG[i][j][r], u = accU[i][j][r];
                float s = g / (1.f + __expf(-g));
                arow_p[nl] = (__bf16)(s * u * w);
            }
        }
    }
}

// ---------------- down GEMM + scatter-add ----------------
__global__ void __launch_bounds__(256, 2)
down_kernel(const __bf16* __restrict__ act,
            const float* __restrict__ dw,
            const int* __restrict__ cnt,
            const int* __restrict__ off,
            const int* __restrict__ row_t,
            float* __restrict__ out) {
    const int e = blockIdx.z;
    const int count = cnt[e];
    const int mt = blockIdx.y;
    if (mt * 128 >= count) return;
    const int h0 = blockIdx.x * 128;
    const int rowbase = off[e] + mt * 128;

    __shared__ __bf16 As[128 * 32];
    __shared__ __bf16 Ws[128 * 32];

    const int tid = threadIdx.x;
    const int wv = tid >> 6, lane = tid & 63;
    const int wr = wv >> 1, wc = wv & 1;
    const int quad = lane >> 4, l16 = lane & 15;

    f32x4 acc[4][4] = {};

    const __bf16* abase = act + (size_t)rowbase * F;
    const float* wbase = dw + (size_t)e * H * F + (size_t)h0 * F;

    const int arow = lane >> 2;
    const int acol = (lane & 3) * 8;
    const int wrow = tid >> 1;
    const int kh = (tid & 1) * 16;

    for (int k0 = 0; k0 < F; k0 += 32) {
#pragma unroll
        for (int i = 0; i < 2; ++i) {
            const int seg = wv * 2 + i;
            const __bf16* gp = abase + (size_t)(seg * 16 + arow) * F + k0 + acol;
            __builtin_amdgcn_global_load_lds(AS1(gp), AS3(As + seg * 512), 16, 0, 0);
        }
        {
            const float4* gp = (const float4*)(wbase + (size_t)wrow * F + k0 + kh);
            float4 f0 = gp[0], f1 = gp[1], f2 = gp[2], f3 = gp[3];
            bf16x8 h0v, h1v;
            h0v[0] = (__bf16)f0.x; h0v[1] = (__bf16)f0.y; h0v[2] = (__bf16)f0.z; h0v[3] = (__bf16)f0.w;
            h0v[4] = (__bf16)f1.x; h0v[5] = (__bf16)f1.y; h0v[6] = (__bf16)f1.z; h0v[7] = (__bf16)f1.w;
            h1v[0] = (__bf16)f2.x; h1v[1] = (__bf16)f2.y; h1v[2] = (__bf16)f2.z; h1v[3] = (__bf16)f2.w;
            h1v[4] = (__bf16)f3.x; h1v[5] = (__bf16)f3.y; h1v[6] = (__bf16)f3.z; h1v[7] = (__bf16)f3.w;
            *(bf16x8*)(Ws + wrow * 32 + kh) = h0v;
            *(bf16x8*)(Ws + wrow * 32 + kh + 8) = h1v;
        }
        __syncthreads();

        bf16x8 af[4], bf[4];
#pragma unroll
        for (int i = 0; i < 4; ++i)
            af[i] = *(const bf16x8*)(As + (wr * 64 + i * 16 + l16) * 32 + quad * 8);
#pragma unroll
        for (int j = 0; j < 4; ++j)
            bf[j] = *(const bf16x8*)(Ws + (wc * 64 + j * 16 + l16) * 32 + quad * 8);
#pragma unroll
        for (int i = 0; i < 4; ++i)
#pragma unroll
            for (int j = 0; j < 4; ++j)
                acc[i][j] = __builtin_amdgcn_mfma_f32_16x16x32_bf16(af[i], bf[j], acc[i][j], 0, 0, 0);
        __syncthreads();
    }

#pragma unroll
    for (int i = 0; i < 4; ++i) {
        const int ml = wr * 64 + i * 16 + quad * 4;
#pragma unroll
        for (int r = 0; r < 4; ++r) {
            const int lr = mt * 128 + ml + r;
            if (lr < count) {
                const int t = row_t[rowbase + ml + r];
                float* orow = out + (size_t)t * H + h0;
#pragma unroll
                for (int j = 0; j < 4; ++j)
                    atomicAdd(&orow[wc * 64 + j * 16 + l16], acc[i][j][r]);
            }
        }
    }
}

extern "C" void kernel_launch(void* const* d_in, const int* in_sizes, int n_in,
                              void* d_out, int out_size, void* d_ws, size_t ws_size,
                              hipStream_t stream) {
    const float* x  = (const float*)d_in[0];
    const float* rw = (const float*)d_in[1];
    const float* gw = (const float*)d_in[2];
    const float* uw = (const float*)d_in[3];
    const float* dw = (const float*)d_in[4];
    float* out = (float*)d_out;
    char* ws = (char*)d_ws;

    int*   cnt    = (int*)(ws + 0);
    int*   off    = (int*)(ws + 256);
    int*   list_t = (int*)(ws + 1024);
    float* list_w = (float*)(ws + 1024 + 65536);
    int*   row_t  = (int*)(ws + 1024 + 2 * 65536);
    float* row_w  = (float*)(ws + 1024 + 2 * 65536 + 20480);
    __bf16* Abuf  = (__bf16*)(ws + 262144);
    __bf16* act   = (__bf16*)(ws + 262144 + (size_t)ROWCAP * H * 2);

    hipMemsetAsync(d_out, 0, (size_t)out_size * sizeof(float), stream);
    hipMemsetAsync(ws, 0, 1024, stream);

    router_kernel<<<T / 4, 256, 0, stream>>>(x, rw, cnt, list_t, list_w);
    offsets_kernel<<<1, 64, 0, stream>>>(cnt, off);
    gather_kernel<<<dim3(T, E), 256, 0, stream>>>(x, cnt, off, list_t, list_w, Abuf, row_t, row_w);
    gateup_kernel<<<dim3(F / 128, T / 128, E), 256, 0, stream>>>(Abuf, gw, uw, cnt, off, row_w, act);
    down_kernel<<<dim3(H / 128, T / 128, E), 256, 0, stream>>>(act, dw, cnt, off, row_t, out);
}